// Round 3
// baseline (702.135 us; speedup 1.0000x reference)
//
#include <hip/hip_runtime.h>

#define NN 50000
#define NE 800000
#define ETOT 850000   // NE + NN self loops
#define INC 128
#define HIDC 64
#define HEADS 4
#define C1 256        // HEADS*HIDC
#define OUTC 32
#define NEG 0.2f
#define EPSV 1e-16f

// workspace element offsets (4-byte units); all multiples of 4 for float4 alignment
#define DEN1  0          // [200000] f
#define DEN2  200000     // [50000]  f
#define CNT   250000     // [50000]  i
#define ZTOT  300000     // zero-init region size (denom1, denom2, counts)
#define OFFS  300000     // [50004]  i
#define CURS  350004     // [50000]  i
#define ASRC1 400004     // [200000] f
#define ADST1 600004     // [200000] f
#define ASRC2 800004     // [50000]  f
#define ADST2 850004     // [50000]  f
#define CSRS  900004     // [850000] i
#define H2OFF 1750004    // [12800000] f
#define H1OFF 14550004   // [12800000] f ; h3 reuses first 1600000 of this after node1
#define WS_NEED_FLOATS 27350004ull

__global__ __launch_bounds__(256) void zero_ws(int* w) {
    int i = blockIdx.x * 256 + threadIdx.x;
    if (i < ZTOT) w[i] = 0;
}

// h1 = x @ W1   [NN,128] x [128,256] -> [NN,256]
__global__ __launch_bounds__(256) void gemm1(const float* __restrict__ x,
                                             const float* __restrict__ W,
                                             float* __restrict__ h1) {
    __shared__ float As[32][68];   // [k][m]
    __shared__ float Bs[32][68];   // [k][n]
    const int m0 = blockIdx.x * 64;
    const int n0 = blockIdx.y * 64;
    const int tid = threadIdx.x;
    const int tx = tid & 15, ty = tid >> 4;
    float acc[4][4] = {};
    for (int k0 = 0; k0 < 128; k0 += 32) {
        #pragma unroll
        for (int i = 0; i < 2; ++i) {
            int idx = tid + i * 256;          // 0..511
            int row = idx >> 3;               // 0..63
            int kv  = idx & 7;
            int gr = m0 + row; if (gr >= NN) gr = NN - 1;
            float4 v = *(const float4*)(x + gr * INC + k0 + kv * 4);
            int kk = kv * 4;
            As[kk + 0][row] = v.x; As[kk + 1][row] = v.y;
            As[kk + 2][row] = v.z; As[kk + 3][row] = v.w;
        }
        #pragma unroll
        for (int i = 0; i < 2; ++i) {
            int idx = tid + i * 256;
            int row = idx >> 4;               // k 0..31
            int nv  = idx & 15;
            float4 v = *(const float4*)(W + (k0 + row) * C1 + n0 + nv * 4);
            *(float4*)&Bs[row][nv * 4] = v;
        }
        __syncthreads();
        #pragma unroll
        for (int k = 0; k < 32; ++k) {
            float a[4], b[4];
            #pragma unroll
            for (int i = 0; i < 4; ++i) a[i] = As[k][ty * 4 + i];
            #pragma unroll
            for (int j = 0; j < 4; ++j) b[j] = Bs[k][tx * 4 + j];
            #pragma unroll
            for (int i = 0; i < 4; ++i)
                #pragma unroll
                for (int j = 0; j < 4; ++j) acc[i][j] += a[i] * b[j];
        }
        __syncthreads();
    }
    #pragma unroll
    for (int i = 0; i < 4; ++i) {
        int gr = m0 + ty * 4 + i;
        if (gr < NN) {
            #pragma unroll
            for (int j = 0; j < 4; ++j)
                h1[gr * C1 + n0 + tx * 4 + j] = acc[i][j];
        }
    }
}

// per-node attention dots, layer 1
__global__ __launch_bounds__(256) void attdot1(const float* __restrict__ h1,
                                               const float* __restrict__ att_src,
                                               const float* __restrict__ att_dst,
                                               float* __restrict__ a_src,
                                               float* __restrict__ a_dst) {
    int wave = threadIdx.x >> 6, lane = threadIdx.x & 63;
    int n = blockIdx.x * 4 + wave;
    if (n >= NN) return;
    const float* row = h1 + (size_t)n * C1;
    float ps[4], pd[4];
    #pragma unroll
    for (int h = 0; h < 4; ++h) {
        float v = row[h * 64 + lane];
        ps[h] = v * att_src[h * 64 + lane];
        pd[h] = v * att_dst[h * 64 + lane];
    }
    #pragma unroll
    for (int m = 32; m; m >>= 1) {
        #pragma unroll
        for (int h = 0; h < 4; ++h) {
            ps[h] += __shfl_xor(ps[h], m);
            pd[h] += __shfl_xor(pd[h], m);
        }
    }
    if (lane == 0) {
        #pragma unroll
        for (int h = 0; h < 4; ++h) {
            a_src[n * 4 + h] = ps[h];
            a_dst[n * 4 + h] = pd[h];
        }
    }
}

// per-edge: accumulate softmax denominators + degree counts
__global__ __launch_bounds__(256) void edge1(const int* __restrict__ ei,
                                             const float* __restrict__ a_src,
                                             const float* __restrict__ a_dst,
                                             float* __restrict__ denom1,
                                             int* __restrict__ counts) {
    int e = blockIdx.x * 256 + threadIdx.x;
    if (e >= ETOT) return;
    int s, d;
    if (e < NE) { s = ei[e]; d = ei[NE + e]; }
    else { s = d = e - NE; }
    float4 as = *(const float4*)(a_src + s * 4);
    float4 ad = *(const float4*)(a_dst + d * 4);
    float v0 = as.x + ad.x, v1 = as.y + ad.y, v2 = as.z + ad.z, v3 = as.w + ad.w;
    v0 = v0 >= 0.f ? v0 : NEG * v0;  v1 = v1 >= 0.f ? v1 : NEG * v1;
    v2 = v2 >= 0.f ? v2 : NEG * v2;  v3 = v3 >= 0.f ? v3 : NEG * v3;
    atomicAdd(&denom1[d * 4 + 0], __expf(v0));
    atomicAdd(&denom1[d * 4 + 1], __expf(v1));
    atomicAdd(&denom1[d * 4 + 2], __expf(v2));
    atomicAdd(&denom1[d * 4 + 3], __expf(v3));
    atomicAdd(&counts[d], 1);
}

// exclusive scan of counts -> offs and curs  (single block, 1024 threads)
__global__ __launch_bounds__(1024) void scan_counts(const int* __restrict__ counts,
                                                    int* __restrict__ offs,
                                                    int* __restrict__ curs) {
    __shared__ int sums[1024];
    const int tid = threadIdx.x;
    const int CH = (NN + 1023) / 1024;   // 49
    int start = tid * CH;
    int end = start + CH; if (end > NN) end = NN; if (start > NN) start = NN;
    int s = 0;
    for (int i = start; i < end; ++i) s += counts[i];
    sums[tid] = s;
    __syncthreads();
    for (int ofs = 1; ofs < 1024; ofs <<= 1) {
        int v = 0;
        if (tid >= ofs) v = sums[tid - ofs];
        __syncthreads();
        sums[tid] += v;
        __syncthreads();
    }
    int run = (tid == 0) ? 0 : sums[tid - 1];
    for (int i = start; i < end; ++i) {
        offs[i] = run; curs[i] = run;
        run += counts[i];
    }
    if (tid == 1023) offs[NN] = sums[1023];
}

__global__ __launch_bounds__(256) void scatter_csr(const int* __restrict__ ei,
                                                   int* __restrict__ curs,
                                                   int* __restrict__ csr_src) {
    int e = blockIdx.x * 256 + threadIdx.x;
    if (e >= ETOT) return;
    int s, d;
    if (e < NE) { s = ei[e]; d = ei[NE + e]; }
    else { s = d = e - NE; }
    int pos = atomicAdd(&curs[d], 1);
    csr_src[pos] = s;
}

// layer-1 aggregation: one wave per node, lane = feature within head; ex recomputed
__global__ __launch_bounds__(256) void node1(const float* __restrict__ h1,
                                             const int* __restrict__ offs,
                                             const int* __restrict__ csr_src,
                                             const float* __restrict__ a_src,
                                             const float* __restrict__ a_dst,
                                             const float* __restrict__ denom1,
                                             const float* __restrict__ b1,
                                             float* __restrict__ h2) {
    int wave = threadIdx.x >> 6, lane = threadIdx.x & 63;
    int n = blockIdx.x * 4 + wave;
    if (n >= NN) return;
    int p0 = offs[n], p1 = offs[n + 1];
    float4 ad = *(const float4*)(a_dst + n * 4);
    float a0 = 0.f, a1 = 0.f, a2 = 0.f, a3 = 0.f;
    for (int p = p0; p < p1; ++p) {
        int s = csr_src[p];
        float4 as = *(const float4*)(a_src + s * 4);
        float v0 = as.x + ad.x, v1 = as.y + ad.y, v2 = as.z + ad.z, v3 = as.w + ad.w;
        v0 = v0 >= 0.f ? v0 : NEG * v0;  v1 = v1 >= 0.f ? v1 : NEG * v1;
        v2 = v2 >= 0.f ? v2 : NEG * v2;  v3 = v3 >= 0.f ? v3 : NEG * v3;
        float e0 = __expf(v0), e1 = __expf(v1), e2 = __expf(v2), e3 = __expf(v3);
        const float* hr = h1 + (size_t)s * C1;
        a0 += hr[lane] * e0;
        a1 += hr[64 + lane] * e1;
        a2 += hr[128 + lane] * e2;
        a3 += hr[192 + lane] * e3;
    }
    float4 den = *(const float4*)(denom1 + n * 4);
    float o0 = a0 / (den.x + EPSV) + b1[lane];
    float o1 = a1 / (den.y + EPSV) + b1[64 + lane];
    float o2 = a2 / (den.z + EPSV) + b1[128 + lane];
    float o3 = a3 / (den.w + EPSV) + b1[192 + lane];
    o0 = o0 > 0.f ? o0 : __expf(o0) - 1.f;
    o1 = o1 > 0.f ? o1 : __expf(o1) - 1.f;
    o2 = o2 > 0.f ? o2 : __expf(o2) - 1.f;
    o3 = o3 > 0.f ? o3 : __expf(o3) - 1.f;
    float* orow = h2 + (size_t)n * C1;
    orow[lane] = o0; orow[64 + lane] = o1; orow[128 + lane] = o2; orow[192 + lane] = o3;
}

// h3 = h2 @ W2   [NN,256] x [256,32] -> [NN,32]
__global__ __launch_bounds__(256) void gemm2(const float* __restrict__ h2,
                                             const float* __restrict__ W,
                                             float* __restrict__ h3) {
    __shared__ float As[32][132];  // [k][m] m=128
    __shared__ float Bs[32][36];   // [k][n] n=32
    const int m0 = blockIdx.x * 128;
    const int tid = threadIdx.x;
    const int tx = tid & 7, ty = tid >> 3;   // ty 0..31 (rows), tx 0..7 (cols)
    float acc[4][4] = {};
    for (int k0 = 0; k0 < 256; k0 += 32) {
        #pragma unroll
        for (int i = 0; i < 4; ++i) {
            int idx = tid + i * 256;          // 0..1023
            int row = idx >> 3;               // 0..127
            int kv  = idx & 7;
            int gr = m0 + row; if (gr >= NN) gr = NN - 1;
            float4 v = *(const float4*)(h2 + (size_t)gr * C1 + k0 + kv * 4);
            int kk = kv * 4;
            As[kk + 0][row] = v.x; As[kk + 1][row] = v.y;
            As[kk + 2][row] = v.z; As[kk + 3][row] = v.w;
        }
        {
            int row = tid >> 3;               // k 0..31
            int nv  = tid & 7;
            float4 v = *(const float4*)(W + (k0 + row) * OUTC + nv * 4);
            *(float4*)&Bs[row][nv * 4] = v;
        }
        __syncthreads();
        #pragma unroll
        for (int k = 0; k < 32; ++k) {
            float a[4], b[4];
            #pragma unroll
            for (int i = 0; i < 4; ++i) a[i] = As[k][ty * 4 + i];
            #pragma unroll
            for (int j = 0; j < 4; ++j) b[j] = Bs[k][tx * 4 + j];
            #pragma unroll
            for (int i = 0; i < 4; ++i)
                #pragma unroll
                for (int j = 0; j < 4; ++j) acc[i][j] += a[i] * b[j];
        }
        __syncthreads();
    }
    #pragma unroll
    for (int i = 0; i < 4; ++i) {
        int gr = m0 + ty * 4 + i;
        if (gr < NN) {
            #pragma unroll
            for (int j = 0; j < 4; ++j)
                h3[(size_t)gr * OUTC + tx * 4 + j] = acc[i][j];
        }
    }
}

// layer-2 attention dots: half-wave (32 lanes) per node
__global__ __launch_bounds__(256) void attdot2(const float* __restrict__ h3,
                                               const float* __restrict__ att_src,
                                               const float* __restrict__ att_dst,
                                               float* __restrict__ a_src,
                                               float* __restrict__ a_dst) {
    int wave = threadIdx.x >> 6, lane = threadIdx.x & 63;
    int half = lane >> 5, c = lane & 31;
    int n = blockIdx.x * 8 + wave * 2 + half;
    if (n >= NN) return;
    float v = h3[(size_t)n * OUTC + c];
    float ps = v * att_src[c];
    float pd = v * att_dst[c];
    #pragma unroll
    for (int m = 16; m; m >>= 1) {
        ps += __shfl_xor(ps, m, 32);
        pd += __shfl_xor(pd, m, 32);
    }
    if (c == 0) { a_src[n] = ps; a_dst[n] = pd; }
}

__global__ __launch_bounds__(256) void edge2(const int* __restrict__ ei,
                                             const float* __restrict__ a_src,
                                             const float* __restrict__ a_dst,
                                             float* __restrict__ denom2) {
    int e = blockIdx.x * 256 + threadIdx.x;
    if (e >= ETOT) return;
    int s, d;
    if (e < NE) { s = ei[e]; d = ei[NE + e]; }
    else { s = d = e - NE; }
    float v = a_src[s] + a_dst[d];
    v = v >= 0.f ? v : NEG * v;
    atomicAdd(&denom2[d], __expf(v));
}

// layer-2 aggregation: half-wave per node, lane = output feature; ex recomputed
__global__ __launch_bounds__(256) void node2(const float* __restrict__ h3,
                                             const int* __restrict__ offs,
                                             const int* __restrict__ csr_src,
                                             const float* __restrict__ a_src,
                                             const float* __restrict__ a_dst,
                                             const float* __restrict__ denom2,
                                             const float* __restrict__ b2,
                                             float* __restrict__ out) {
    int wave = threadIdx.x >> 6, lane = threadIdx.x & 63;
    int half = lane >> 5, c = lane & 31;
    int n = blockIdx.x * 8 + wave * 2 + half;
    if (n >= NN) return;
    int p0 = offs[n], p1 = offs[n + 1];
    float adn = a_dst[n];
    float acc = 0.f;
    for (int p = p0; p < p1; ++p) {
        int s = csr_src[p];
        float v = a_src[s] + adn;
        v = v >= 0.f ? v : NEG * v;
        acc += h3[(size_t)s * OUTC + c] * __expf(v);
    }
    out[(size_t)n * OUTC + c] = acc / (denom2[n] + EPSV) + b2[c];
}

extern "C" void kernel_launch(void* const* d_in, const int* in_sizes, int n_in,
                              void* d_out, int out_size, void* d_ws, size_t ws_size,
                              hipStream_t stream) {
    // diagnostic guard: if workspace too small, do nothing (fail absmax, not crash)
    if (ws_size < WS_NEED_FLOATS * 4ull) return;

    const float* x        = (const float*)d_in[0];
    const int* ei         = (const int*)d_in[1];   // harness passes integer inputs as int32
    const float* W1       = (const float*)d_in[2];
    const float* att_src1 = (const float*)d_in[3];
    const float* att_dst1 = (const float*)d_in[4];
    const float* b1       = (const float*)d_in[5];
    const float* W2       = (const float*)d_in[6];
    const float* att_src2 = (const float*)d_in[7];
    const float* att_dst2 = (const float*)d_in[8];
    const float* b2       = (const float*)d_in[9];
    float* out = (float*)d_out;
    float* ws  = (float*)d_ws;
    int*   wsi = (int*)d_ws;

    float* denom1 = ws + DEN1;
    float* denom2 = ws + DEN2;
    int*   counts = wsi + CNT;
    int*   offs   = wsi + OFFS;
    int*   curs   = wsi + CURS;
    float* a_src1 = ws + ASRC1;
    float* a_dst1 = ws + ADST1;
    float* a_src2 = ws + ASRC2;
    float* a_dst2 = ws + ADST2;
    int*   csr_s  = wsi + CSRS;
    float* h2     = ws + H2OFF;
    float* h1     = ws + H1OFF;
    float* h3     = ws + H1OFF;   // reuse h1 region after node1

    const int EB = (ETOT + 255) / 256;

    hipLaunchKernelGGL(zero_ws, dim3((ZTOT + 255) / 256), dim3(256), 0, stream, wsi);
    hipLaunchKernelGGL(gemm1, dim3((NN + 63) / 64, 4), dim3(256), 0, stream, x, W1, h1);
    hipLaunchKernelGGL(attdot1, dim3((NN + 3) / 4), dim3(256), 0, stream,
                       h1, att_src1, att_dst1, a_src1, a_dst1);
    hipLaunchKernelGGL(edge1, dim3(EB), dim3(256), 0, stream,
                       ei, a_src1, a_dst1, denom1, counts);
    hipLaunchKernelGGL(scan_counts, dim3(1), dim3(1024), 0, stream, counts, offs, curs);
    hipLaunchKernelGGL(scatter_csr, dim3(EB), dim3(256), 0, stream, ei, curs, csr_s);
    hipLaunchKernelGGL(node1, dim3((NN + 3) / 4), dim3(256), 0, stream,
                       h1, offs, csr_s, a_src1, a_dst1, denom1, b1, h2);
    hipLaunchKernelGGL(gemm2, dim3((NN + 127) / 128), dim3(256), 0, stream, h2, W2, h3);
    hipLaunchKernelGGL(attdot2, dim3((NN + 7) / 8), dim3(256), 0, stream,
                       h3, att_src2, att_dst2, a_src2, a_dst2);
    hipLaunchKernelGGL(edge2, dim3(EB), dim3(256), 0, stream, ei, a_src2, a_dst2, denom2);
    hipLaunchKernelGGL(node2, dim3((NN + 7) / 8), dim3(256), 0, stream,
                       h3, offs, csr_s, a_src2, a_dst2, denom2, b2, out);
}

// Round 4
// 498.745 us; speedup vs baseline: 1.4078x; 1.4078x over previous
//
#include <hip/hip_runtime.h>

#define NN 50000
#define NE 800000
#define ETOT 850000   // NE + NN self loops
#define INC 128
#define HIDC 64
#define HEADS 4
#define C1 256        // HEADS*HIDC
#define OUTC 32
#define NEG 0.2f
#define EPSV 1e-16f

// workspace element offsets (4-byte units); all multiples of 4 for float4 alignment
#define CNT   0          // [50000]  i  (zeroed)
#define ZTOT  50000      // zero-init region
#define OFFS  50000      // [50004]  i
#define CURS  100004     // [50000]  i
#define ASRC1 150004     // [200000] f
#define ADST1 350004     // [200000] f
#define ASRC2 550004     // [50000]  f
#define ADST2 600004     // [50000]  f
#define CSRS  650004     // [850000] i
#define H2OFF 1500004    // [12800000] f
#define H1OFF 14300004   // [12800000] f ; h3 reuses first 1600000 after node1
#define WS_NEED_FLOATS 27100004ull

__global__ __launch_bounds__(256) void zero_ws(int* w) {
    int i = blockIdx.x * 256 + threadIdx.x;
    if (i < ZTOT) w[i] = 0;
}

// h1 = x @ W1   [NN,128] x [128,256] -> [NN,256]
__global__ __launch_bounds__(256) void gemm1(const float* __restrict__ x,
                                             const float* __restrict__ W,
                                             float* __restrict__ h1) {
    __shared__ float As[32][68];   // [k][m]
    __shared__ float Bs[32][68];   // [k][n]
    const int m0 = blockIdx.x * 64;
    const int n0 = blockIdx.y * 64;
    const int tid = threadIdx.x;
    const int tx = tid & 15, ty = tid >> 4;
    float acc[4][4] = {};
    for (int k0 = 0; k0 < 128; k0 += 32) {
        #pragma unroll
        for (int i = 0; i < 2; ++i) {
            int idx = tid + i * 256;          // 0..511
            int row = idx >> 3;               // 0..63
            int kv  = idx & 7;
            int gr = m0 + row; if (gr >= NN) gr = NN - 1;
            float4 v = *(const float4*)(x + gr * INC + k0 + kv * 4);
            int kk = kv * 4;
            As[kk + 0][row] = v.x; As[kk + 1][row] = v.y;
            As[kk + 2][row] = v.z; As[kk + 3][row] = v.w;
        }
        #pragma unroll
        for (int i = 0; i < 2; ++i) {
            int idx = tid + i * 256;
            int row = idx >> 4;               // k 0..31
            int nv  = idx & 15;
            float4 v = *(const float4*)(W + (k0 + row) * C1 + n0 + nv * 4);
            *(float4*)&Bs[row][nv * 4] = v;
        }
        __syncthreads();
        #pragma unroll
        for (int k = 0; k < 32; ++k) {
            float a[4], b[4];
            #pragma unroll
            for (int i = 0; i < 4; ++i) a[i] = As[k][ty * 4 + i];
            #pragma unroll
            for (int j = 0; j < 4; ++j) b[j] = Bs[k][tx * 4 + j];
            #pragma unroll
            for (int i = 0; i < 4; ++i)
                #pragma unroll
                for (int j = 0; j < 4; ++j) acc[i][j] += a[i] * b[j];
        }
        __syncthreads();
    }
    #pragma unroll
    for (int i = 0; i < 4; ++i) {
        int gr = m0 + ty * 4 + i;
        if (gr < NN) {
            #pragma unroll
            for (int j = 0; j < 4; ++j)
                h1[gr * C1 + n0 + tx * 4 + j] = acc[i][j];
        }
    }
}

// per-node attention dots, layer 1
__global__ __launch_bounds__(256) void attdot1(const float* __restrict__ h1,
                                               const float* __restrict__ att_src,
                                               const float* __restrict__ att_dst,
                                               float* __restrict__ a_src,
                                               float* __restrict__ a_dst) {
    int wave = threadIdx.x >> 6, lane = threadIdx.x & 63;
    int n = blockIdx.x * 4 + wave;
    if (n >= NN) return;
    const float* row = h1 + (size_t)n * C1;
    float ps[4], pd[4];
    #pragma unroll
    for (int h = 0; h < 4; ++h) {
        float v = row[h * 64 + lane];
        ps[h] = v * att_src[h * 64 + lane];
        pd[h] = v * att_dst[h * 64 + lane];
    }
    #pragma unroll
    for (int m = 32; m; m >>= 1) {
        #pragma unroll
        for (int h = 0; h < 4; ++h) {
            ps[h] += __shfl_xor(ps[h], m);
            pd[h] += __shfl_xor(pd[h], m);
        }
    }
    if (lane == 0) {
        #pragma unroll
        for (int h = 0; h < 4; ++h) {
            a_src[n * 4 + h] = ps[h];
            a_dst[n * 4 + h] = pd[h];
        }
    }
}

// degree histogram: 1 int atomic per edge
__global__ __launch_bounds__(256) void hist(const int* __restrict__ ei,
                                            int* __restrict__ counts) {
    int e = blockIdx.x * 256 + threadIdx.x;
    if (e >= ETOT) return;
    int d = (e < NE) ? ei[NE + e] : (e - NE);
    atomicAdd(&counts[d], 1);
}

// exclusive scan of counts -> offs and curs  (single block, 1024 threads)
__global__ __launch_bounds__(1024) void scan_counts(const int* __restrict__ counts,
                                                    int* __restrict__ offs,
                                                    int* __restrict__ curs) {
    __shared__ int sums[1024];
    const int tid = threadIdx.x;
    const int CH = (NN + 1023) / 1024;   // 49
    int start = tid * CH;
    int end = start + CH; if (end > NN) end = NN; if (start > NN) start = NN;
    int s = 0;
    for (int i = start; i < end; ++i) s += counts[i];
    sums[tid] = s;
    __syncthreads();
    for (int ofs = 1; ofs < 1024; ofs <<= 1) {
        int v = 0;
        if (tid >= ofs) v = sums[tid - ofs];
        __syncthreads();
        sums[tid] += v;
        __syncthreads();
    }
    int run = (tid == 0) ? 0 : sums[tid - 1];
    for (int i = start; i < end; ++i) {
        offs[i] = run; curs[i] = run;
        run += counts[i];
    }
    if (tid == 1023) offs[NN] = sums[1023];
}

__global__ __launch_bounds__(256) void scatter_csr(const int* __restrict__ ei,
                                                   int* __restrict__ curs,
                                                   int* __restrict__ csr_src) {
    int e = blockIdx.x * 256 + threadIdx.x;
    if (e >= ETOT) return;
    int s, d;
    if (e < NE) { s = ei[e]; d = ei[NE + e]; }
    else { s = d = e - NE; }
    int pos = atomicAdd(&curs[d], 1);
    csr_src[pos] = s;
}

// layer-1 aggregation: one wave per node; denom accumulated in-register
__global__ __launch_bounds__(256) void node1(const float* __restrict__ h1,
                                             const int* __restrict__ offs,
                                             const int* __restrict__ csr_src,
                                             const float* __restrict__ a_src,
                                             const float* __restrict__ a_dst,
                                             const float* __restrict__ b1,
                                             float* __restrict__ h2) {
    int wave = threadIdx.x >> 6, lane = threadIdx.x & 63;
    int n = blockIdx.x * 4 + wave;
    if (n >= NN) return;
    int p0 = offs[n], p1 = offs[n + 1];
    float4 ad = *(const float4*)(a_dst + n * 4);
    float a0 = 0.f, a1 = 0.f, a2 = 0.f, a3 = 0.f;
    float den0 = 0.f, den1v = 0.f, den2v = 0.f, den3 = 0.f;
    for (int p = p0; p < p1; ++p) {
        int s = csr_src[p];
        float4 as = *(const float4*)(a_src + s * 4);
        float v0 = as.x + ad.x, v1 = as.y + ad.y, v2 = as.z + ad.z, v3 = as.w + ad.w;
        v0 = v0 >= 0.f ? v0 : NEG * v0;  v1 = v1 >= 0.f ? v1 : NEG * v1;
        v2 = v2 >= 0.f ? v2 : NEG * v2;  v3 = v3 >= 0.f ? v3 : NEG * v3;
        float e0 = __expf(v0), e1 = __expf(v1), e2 = __expf(v2), e3 = __expf(v3);
        den0 += e0; den1v += e1; den2v += e2; den3 += e3;
        const float* hr = h1 + (size_t)s * C1;
        a0 += hr[lane] * e0;
        a1 += hr[64 + lane] * e1;
        a2 += hr[128 + lane] * e2;
        a3 += hr[192 + lane] * e3;
    }
    float o0 = a0 / (den0 + EPSV) + b1[lane];
    float o1 = a1 / (den1v + EPSV) + b1[64 + lane];
    float o2 = a2 / (den2v + EPSV) + b1[128 + lane];
    float o3 = a3 / (den3 + EPSV) + b1[192 + lane];
    o0 = o0 > 0.f ? o0 : __expf(o0) - 1.f;
    o1 = o1 > 0.f ? o1 : __expf(o1) - 1.f;
    o2 = o2 > 0.f ? o2 : __expf(o2) - 1.f;
    o3 = o3 > 0.f ? o3 : __expf(o3) - 1.f;
    float* orow = h2 + (size_t)n * C1;
    orow[lane] = o0; orow[64 + lane] = o1; orow[128 + lane] = o2; orow[192 + lane] = o3;
}

// h3 = h2 @ W2   [NN,256] x [256,32] -> [NN,32]
__global__ __launch_bounds__(256) void gemm2(const float* __restrict__ h2,
                                             const float* __restrict__ W,
                                             float* __restrict__ h3) {
    __shared__ float As[32][132];  // [k][m] m=128
    __shared__ float Bs[32][36];   // [k][n] n=32
    const int m0 = blockIdx.x * 128;
    const int tid = threadIdx.x;
    const int tx = tid & 7, ty = tid >> 3;   // ty 0..31 (rows), tx 0..7 (cols)
    float acc[4][4] = {};
    for (int k0 = 0; k0 < 256; k0 += 32) {
        #pragma unroll
        for (int i = 0; i < 4; ++i) {
            int idx = tid + i * 256;          // 0..1023
            int row = idx >> 3;               // 0..127
            int kv  = idx & 7;
            int gr = m0 + row; if (gr >= NN) gr = NN - 1;
            float4 v = *(const float4*)(h2 + (size_t)gr * C1 + k0 + kv * 4);
            int kk = kv * 4;
            As[kk + 0][row] = v.x; As[kk + 1][row] = v.y;
            As[kk + 2][row] = v.z; As[kk + 3][row] = v.w;
        }
        {
            int row = tid >> 3;               // k 0..31
            int nv  = tid & 7;
            float4 v = *(const float4*)(W + (k0 + row) * OUTC + nv * 4);
            *(float4*)&Bs[row][nv * 4] = v;
        }
        __syncthreads();
        #pragma unroll
        for (int k = 0; k < 32; ++k) {
            float a[4], b[4];
            #pragma unroll
            for (int i = 0; i < 4; ++i) a[i] = As[k][ty * 4 + i];
            #pragma unroll
            for (int j = 0; j < 4; ++j) b[j] = Bs[k][tx * 4 + j];
            #pragma unroll
            for (int i = 0; i < 4; ++i)
                #pragma unroll
                for (int j = 0; j < 4; ++j) acc[i][j] += a[i] * b[j];
        }
        __syncthreads();
    }
    #pragma unroll
    for (int i = 0; i < 4; ++i) {
        int gr = m0 + ty * 4 + i;
        if (gr < NN) {
            #pragma unroll
            for (int j = 0; j < 4; ++j)
                h3[(size_t)gr * OUTC + tx * 4 + j] = acc[i][j];
        }
    }
}

// layer-2 attention dots: half-wave (32 lanes) per node
__global__ __launch_bounds__(256) void attdot2(const float* __restrict__ h3,
                                               const float* __restrict__ att_src,
                                               const float* __restrict__ att_dst,
                                               float* __restrict__ a_src,
                                               float* __restrict__ a_dst) {
    int wave = threadIdx.x >> 6, lane = threadIdx.x & 63;
    int half = lane >> 5, c = lane & 31;
    int n = blockIdx.x * 8 + wave * 2 + half;
    if (n >= NN) return;
    float v = h3[(size_t)n * OUTC + c];
    float ps = v * att_src[c];
    float pd = v * att_dst[c];
    #pragma unroll
    for (int m = 16; m; m >>= 1) {
        ps += __shfl_xor(ps, m, 32);
        pd += __shfl_xor(pd, m, 32);
    }
    if (c == 0) { a_src[n] = ps; a_dst[n] = pd; }
}

// layer-2 aggregation: half-wave per node; denom in-register
__global__ __launch_bounds__(256) void node2(const float* __restrict__ h3,
                                             const int* __restrict__ offs,
                                             const int* __restrict__ csr_src,
                                             const float* __restrict__ a_src,
                                             const float* __restrict__ a_dst,
                                             const float* __restrict__ b2,
                                             float* __restrict__ out) {
    int wave = threadIdx.x >> 6, lane = threadIdx.x & 63;
    int half = lane >> 5, c = lane & 31;
    int n = blockIdx.x * 8 + wave * 2 + half;
    if (n >= NN) return;
    int p0 = offs[n], p1 = offs[n + 1];
    float adn = a_dst[n];
    float acc = 0.f, den = 0.f;
    for (int p = p0; p < p1; ++p) {
        int s = csr_src[p];
        float v = a_src[s] + adn;
        v = v >= 0.f ? v : NEG * v;
        float ex = __expf(v);
        den += ex;
        acc += h3[(size_t)s * OUTC + c] * ex;
    }
    out[(size_t)n * OUTC + c] = acc / (den + EPSV) + b2[c];
}

extern "C" void kernel_launch(void* const* d_in, const int* in_sizes, int n_in,
                              void* d_out, int out_size, void* d_ws, size_t ws_size,
                              hipStream_t stream) {
    if (ws_size < WS_NEED_FLOATS * 4ull) return;

    const float* x        = (const float*)d_in[0];
    const int* ei         = (const int*)d_in[1];   // harness passes integer inputs as int32
    const float* W1       = (const float*)d_in[2];
    const float* att_src1 = (const float*)d_in[3];
    const float* att_dst1 = (const float*)d_in[4];
    const float* b1       = (const float*)d_in[5];
    const float* W2       = (const float*)d_in[6];
    const float* att_src2 = (const float*)d_in[7];
    const float* att_dst2 = (const float*)d_in[8];
    const float* b2       = (const float*)d_in[9];
    float* out = (float*)d_out;
    float* ws  = (float*)d_ws;
    int*   wsi = (int*)d_ws;

    int*   counts = wsi + CNT;
    int*   offs   = wsi + OFFS;
    int*   curs   = wsi + CURS;
    float* a_src1 = ws + ASRC1;
    float* a_dst1 = ws + ADST1;
    float* a_src2 = ws + ASRC2;
    float* a_dst2 = ws + ADST2;
    int*   csr_s  = wsi + CSRS;
    float* h2     = ws + H2OFF;
    float* h1     = ws + H1OFF;
    float* h3     = ws + H1OFF;   // reuse h1 region after node1

    const int EB = (ETOT + 255) / 256;

    hipLaunchKernelGGL(zero_ws, dim3((ZTOT + 255) / 256), dim3(256), 0, stream, wsi);
    hipLaunchKernelGGL(gemm1, dim3((NN + 63) / 64, 4), dim3(256), 0, stream, x, W1, h1);
    hipLaunchKernelGGL(attdot1, dim3((NN + 3) / 4), dim3(256), 0, stream,
                       h1, att_src1, att_dst1, a_src1, a_dst1);
    hipLaunchKernelGGL(hist, dim3(EB), dim3(256), 0, stream, ei, counts);
    hipLaunchKernelGGL(scan_counts, dim3(1), dim3(1024), 0, stream, counts, offs, curs);
    hipLaunchKernelGGL(scatter_csr, dim3(EB), dim3(256), 0, stream, ei, curs, csr_s);
    hipLaunchKernelGGL(node1, dim3((NN + 3) / 4), dim3(256), 0, stream,
                       h1, offs, csr_s, a_src1, a_dst1, b1, h2);
    hipLaunchKernelGGL(gemm2, dim3((NN + 127) / 128), dim3(256), 0, stream, h2, W2, h3);
    hipLaunchKernelGGL(attdot2, dim3((NN + 7) / 8), dim3(256), 0, stream,
                       h3, att_src2, att_dst2, a_src2, a_dst2);
    hipLaunchKernelGGL(node2, dim3((NN + 7) / 8), dim3(256), 0, stream,
                       h3, offs, csr_s, a_src2, a_dst2, b2, out);
}